// Round 16
// baseline (283.894 us; speedup 1.0000x reference)
//
#include <hip/hip_runtime.h>
#include <cstdint>
#include <cstddef>

constexpr int DIMS = 128;

typedef __attribute__((ext_vector_type(8))) short bf16x8;
typedef __attribute__((ext_vector_type(8))) unsigned short ushort8v;
typedef __attribute__((ext_vector_type(4))) float f32x4;
typedef __attribute__((ext_vector_type(2))) float f32x2;

#if defined(__has_builtin)
# if __has_builtin(__builtin_amdgcn_cvt_pk_f32_fp8) && __has_builtin(__builtin_amdgcn_cvt_pk_fp8_f32)
#  define FP8_HW 1
# endif
#endif
#ifndef FP8_HW
# define FP8_HW 0
#endif

__device__ __forceinline__ unsigned short f2b(float f) {
    uint32_t u = __builtin_bit_cast(uint32_t, f);
    uint32_t r = (u + 0x7FFFu + ((u >> 16) & 1u)) >> 16;
    return (unsigned short)r;
}
__device__ __forceinline__ float b2f(unsigned short h) {
    uint32_t u = ((uint32_t)h) << 16;
    return __builtin_bit_cast(float, u);
}

// ---- fp8 e4m3fn helpers (HW cvt when available; manual fallback otherwise) ----
__device__ __forceinline__ float q2f_sw(unsigned char v) {
    uint32_t em = v & 0x7fu;
    float mag;
    if (em >= 0x08u) {
        uint32_t bits = (((em >> 3) + 120u) << 23) | ((em & 7u) << 20);
        mag = __builtin_bit_cast(float, bits);
    } else {
        mag = (float)em * 0.001953125f;
    }
    return (v & 0x80u) ? -mag : mag;
}
__device__ __forceinline__ unsigned char f2q_sw(float f) {
    uint32_t u = __builtin_bit_cast(uint32_t, f);
    uint32_t s = (u >> 24) & 0x80u;
    int e = (int)((u >> 23) & 0xffu) - 127;
    uint32_t m = u & 0x7fffffu;
    if (e < -9) return (unsigned char)s;
    if (e > 8) return (unsigned char)(s | 0x7eu);
    if (e >= -6) {
        uint32_t mant = m >> 20;
        uint32_t rem = m & 0xfffffu;
        uint32_t r = mant + ((rem > 0x80000u) || (rem == 0x80000u && (mant & 1u)));
        uint32_t v = (((uint32_t)(e + 7)) << 3) + r;
        if (v >= 0x7fu) v = 0x7eu;
        return (unsigned char)(s | v);
    }
    float scaled = fabsf(f) * 512.0f;
    int q = (int)(scaled + 0.5f);
    if (q > 8) q = 8;
    return (unsigned char)(s | (uint32_t)q);
}

__device__ __forceinline__ void fp8x8_fma(uint2 v, float w, float* acc) {
#if FP8_HW
    f32x2 a0 = __builtin_amdgcn_cvt_pk_f32_fp8((int)v.x, false);
    f32x2 a1 = __builtin_amdgcn_cvt_pk_f32_fp8((int)v.x, true);
    f32x2 a2 = __builtin_amdgcn_cvt_pk_f32_fp8((int)v.y, false);
    f32x2 a3 = __builtin_amdgcn_cvt_pk_f32_fp8((int)v.y, true);
    acc[0] = fmaf(w, a0[0], acc[0]); acc[1] = fmaf(w, a0[1], acc[1]);
    acc[2] = fmaf(w, a1[0], acc[2]); acc[3] = fmaf(w, a1[1], acc[3]);
    acc[4] = fmaf(w, a2[0], acc[4]); acc[5] = fmaf(w, a2[1], acc[5]);
    acc[6] = fmaf(w, a3[0], acc[6]); acc[7] = fmaf(w, a3[1], acc[7]);
#else
#pragma unroll
    for (int q = 0; q < 8; ++q) {
        unsigned char b = (unsigned char)(((q < 4 ? v.x : v.y) >> ((q & 3) * 8)) & 0xffu);
        acc[q] = fmaf(w, q2f_sw(b), acc[q]);
    }
#endif
}

__device__ __forceinline__ unsigned int fp8x4_pack(float a, float b, float c, float d) {
#if FP8_HW
    int r = 0;
    r = __builtin_amdgcn_cvt_pk_fp8_f32(a, b, r, false);
    r = __builtin_amdgcn_cvt_pk_fp8_f32(c, d, r, true);
    return (unsigned int)r;
#else
    return (unsigned int)f2q_sw(a) | ((unsigned int)f2q_sw(b) << 8) |
           ((unsigned int)f2q_sw(c) << 16) | ((unsigned int)f2q_sw(d) << 24);
#endif
}

// ================= bucketed CSR build (LDS atomics, packed edges) =================
__global__ __launch_bounds__(1024) void k_bhist(const int* __restrict__ dst,
                                                int* __restrict__ bktCnt,
                                                int E, int nbkt, int Ec) {
    __shared__ int lh[512];
    if (threadIdx.x < 512) lh[threadIdx.x] = 0;
    __syncthreads();
    int base = blockIdx.x * Ec;
    int end = min(E, base + Ec);
    for (int i = base + threadIdx.x; i < end; i += 1024)
        atomicAdd(&lh[dst[i] >> 9], 1);
    __syncthreads();
    if (threadIdx.x < nbkt) {
        int v = lh[threadIdx.x];
        if (v) atomicAdd(&bktCnt[threadIdx.x * 16], v);
    }
}

__global__ void k_bscan(const int* __restrict__ bktCnt, int* __restrict__ bktBase,
                        int* __restrict__ bktCursor, int nbkt, int E) {
    int lane = threadIdx.x;  // blockDim.x == 64
    int v[8]; int s = 0;
#pragma unroll
    for (int k = 0; k < 8; ++k) {
        int idx = lane * 8 + k;
        int c = (idx < nbkt) ? bktCnt[idx * 16] : 0;
        v[k] = s; s += c;
    }
    int x = s;
#pragma unroll
    for (int d = 1; d < 64; d <<= 1) {
        int y = __shfl_up(x, d);
        if (lane >= d) x += y;
    }
    int excl = x - s;
#pragma unroll
    for (int k = 0; k < 8; ++k) {
        int idx = lane * 8 + k;
        if (idx < nbkt) { int bb = excl + v[k]; bktBase[idx] = bb; bktCursor[idx * 16] = bb; }
    }
    if (lane == 0) bktBase[nbkt] = E;
}

__global__ __launch_bounds__(1024) void k_bscatter(const int* __restrict__ src,
                                                   const int* __restrict__ dst,
                                                   int* __restrict__ bktCursor,
                                                   unsigned int* __restrict__ epk,
                                                   int E, int nbkt, int Ec) {
    __shared__ int lh[512];
    __shared__ int lbase[512];
    __shared__ int lcur[512];
    if (threadIdx.x < 512) { lh[threadIdx.x] = 0; lcur[threadIdx.x] = 0; }
    __syncthreads();
    int base = blockIdx.x * Ec;
    int end = min(E, base + Ec);
    for (int i = base + threadIdx.x; i < end; i += 1024)
        atomicAdd(&lh[dst[i] >> 9], 1);
    __syncthreads();
    if (threadIdx.x < nbkt) {
        int c = lh[threadIdx.x];
        lbase[threadIdx.x] = c ? atomicAdd(&bktCursor[threadIdx.x * 16], c) : 0;
    }
    __syncthreads();
    for (int i = base + threadIdx.x; i < end; i += 1024) {
        int d = dst[i], s = src[i];
        int b = d >> 9;
        int r = atomicAdd(&lcur[b], 1);
        epk[lbase[b] + r] = ((unsigned int)s << 9) | (unsigned int)(d & 511);
    }
}

__global__ __launch_bounds__(512) void k_bcsr(const unsigned int* __restrict__ epk,
                                              const int* __restrict__ bktBase,
                                              int* __restrict__ col, int* __restrict__ row_ptr,
                                              int* __restrict__ cnt, float* __restrict__ dinv,
                                              int N) {
    __shared__ int lcnt[512];
    __shared__ int loff[512];
    __shared__ int lcur[512];
    const int b = blockIdx.x;
    const int node0 = b << 9;
    lcnt[threadIdx.x] = 0; lcur[threadIdx.x] = 0;
    __syncthreads();
    const int ebeg = bktBase[b], eend = bktBase[b + 1];
    for (int i = ebeg + threadIdx.x; i < eend; i += 512)
        atomicAdd(&lcnt[epk[i] & 511u], 1);
    __syncthreads();
    if (threadIdx.x < 64) {
        int lane = threadIdx.x;
        int v[8]; int s = 0;
#pragma unroll
        for (int k = 0; k < 8; ++k) { v[k] = s; s += lcnt[lane * 8 + k]; }
        int x = s;
#pragma unroll
        for (int d = 1; d < 64; d <<= 1) { int y = __shfl_up(x, d); if (lane >= d) x += y; }
        int excl = x - s;
#pragma unroll
        for (int k = 0; k < 8; ++k) loff[lane * 8 + k] = excl + v[k];
    }
    __syncthreads();
    const int node = node0 + threadIdx.x;
    if (node < N) {
        int c = lcnt[threadIdx.x];
        row_ptr[node] = ebeg + loff[threadIdx.x];
        cnt[node] = c;
        dinv[node] = rsqrtf((float)(c + 1));
    }
    for (int i = ebeg + threadIdx.x; i < eend; i += 512) {
        unsigned int e = epk[i];
        int dl = e & 511u;
        int r = atomicAdd(&lcur[dl], 1);
        col[ebeg + loff[dl] + r] = (int)(e >> 9);
    }
}

// ================= old-path CSR kernels (fallback when nbkt > 512) =================
__global__ void k_count_slot(const int* __restrict__ dst, int* __restrict__ cnt,
                             int* __restrict__ slot, int E) {
    int e = blockIdx.x * blockDim.x + threadIdx.x;
    if (e < E) slot[e] = atomicAdd(&cnt[dst[e]], 1);
}

__global__ void k_alloc(const int* __restrict__ cnt, int* __restrict__ row_ptr,
                        int* __restrict__ bump, int N) {
    int i = blockIdx.x * blockDim.x + threadIdx.x;
    int lane = threadIdx.x & 63;
    int v = (i < N) ? cnt[i] : 0;
    int x = v;
#pragma unroll
    for (int d = 1; d < 64; d <<= 1) {
        int y = __shfl_up(x, d);
        if (lane >= d) x += y;
    }
    int total = __shfl(x, 63);
    int base = 0;
    if (lane == 0) base = atomicAdd(bump, total);
    base = __shfl(base, 0);
    if (i < N) row_ptr[i] = base + x - v;
}

__global__ void k_fill3(const int* __restrict__ src, const int* __restrict__ dst,
                        const int* __restrict__ row_ptr, const int* __restrict__ slot,
                        int* __restrict__ col, int E) {
    int e = blockIdx.x * blockDim.x + threadIdx.x;
    if (e >= E) return;
    col[row_ptr[dst[e]] + slot[e]] = src[e];
}

__global__ void k_dinv2(const int* __restrict__ cnt, float* __restrict__ dinv, int N) {
    int i = blockIdx.x * blockDim.x + threadIdx.x;
    if (i < N) dinv[i] = rsqrtf((float)(cnt[i] + 1));
}

// ---------------- f32 -> fp8 cast (8 elems/thread) ----------------
__global__ void k_cast_q(const float* __restrict__ X, unsigned char* __restrict__ Yq, int n8) {
    int i = blockIdx.x * blockDim.x + threadIdx.x;
    if (i >= n8) return;
    const float4* p = (const float4*)X + (size_t)i * 2;
    float4 a = p[0], b = p[1];
    uint2 q;
    q.x = fp8x4_pack(a.x, a.y, a.z, a.w);
    q.y = fp8x4_pack(b.x, b.y, b.z, b.w);
    *(uint2*)&Yq[(size_t)i * 8] = q;
}

__global__ void k_wpack4(const float* __restrict__ W0, const float* __restrict__ W1,
                         const float* __restrict__ W2, const float* __restrict__ W3,
                         unsigned short* __restrict__ out) {
    int t = blockIdx.x * blockDim.x + threadIdx.x;  // 0..2047
    if (t >= 2048) return;
    const float* W = (blockIdx.y == 0) ? W0 : (blockIdx.y == 1) ? W1
                   : (blockIdx.y == 2) ? W2 : W3;
    unsigned short* o = out + (size_t)blockIdx.y * 16384;
    int lane = t & 63;
    int nt = (t >> 6) & 7;
    int kk = t >> 9;
    int n = nt * 16 + (lane & 15);
    int k0 = kk * 32 + (lane >> 4) * 8;
    ushort8v h8;
#pragma unroll
    for (int j = 0; j < 8; ++j) h8[j] = f2b(W[(size_t)(k0 + j) * DIMS + n]);
    *(ushort8v*)&o[(size_t)t * 8] = h8;
}

// ---------------- gather: fp8 neighbors + f32 self, f32 accum, bf16 out ----------------
__global__ __launch_bounds__(256) void k_gather_q2(
    const unsigned char* __restrict__ Xq, const float* __restrict__ Xf,
    const float* __restrict__ dinv,
    const int* __restrict__ row_ptr, const int* __restrict__ cnt,
    const int* __restrict__ col, unsigned short* __restrict__ aggb, int N)
{
    int t = blockIdx.x * blockDim.x + threadIdx.x;
    int node = t >> 4;
    if (node >= N) return;
    const size_t base = (size_t)(t & 15) * 8;

    float ds = dinv[node];
    float w0 = ds * ds;
    const float4* sp = (const float4*)&Xf[(size_t)node * DIMS + base];
    float4 s0v = sp[0], s1v = sp[1];
    float acc[8];
    acc[0] = s0v.x * w0; acc[1] = s0v.y * w0; acc[2] = s0v.z * w0; acc[3] = s0v.w * w0;
    acc[4] = s1v.x * w0; acc[5] = s1v.y * w0; acc[6] = s1v.z * w0; acc[7] = s1v.w * w0;

    const int beg = row_ptr[node];
    const int m = cnt[node];
    int j = 0;
    for (; j + 1 < m; j += 2) {
        int n0 = col[beg + j], n1 = col[beg + j + 1];
        float wa = ds * dinv[n0], wb = ds * dinv[n1];
        uint2 v0 = *(const uint2*)&Xq[(size_t)n0 * DIMS + base];
        uint2 v1 = *(const uint2*)&Xq[(size_t)n1 * DIMS + base];
        fp8x8_fma(v0, wa, acc);
        fp8x8_fma(v1, wb, acc);
    }
    if (j < m) {
        int n0 = col[beg + j];
        float wa = ds * dinv[n0];
        uint2 v0 = *(const uint2*)&Xq[(size_t)n0 * DIMS + base];
        fp8x8_fma(v0, wa, acc);
    }
    ushort8v o;
#pragma unroll
    for (int q = 0; q < 8; ++q) o[q] = f2b(acc[q]);
    *(ushort8v*)&aggb[(size_t)node * DIMS + base] = o;
}

// ---------------- MFMA dual-GEMM + coupling, v6: QUARTER-column blocks, 16KB LDS ----------------
// Block = 64 rows x 32 cols (quarter h of 128). 8 blocks/CU -> full wave occupancy.
__global__ __launch_bounds__(256) void k_mfma_couple6(
    const unsigned short* __restrict__ Ab, const unsigned short* __restrict__ Wpk,
    const float* __restrict__ bs, const float* __restrict__ bt,
    const float* __restrict__ Xo, float* __restrict__ Out,
    unsigned char* Out8, int N, int nidx)
{
    __shared__ unsigned short lds[8192];  // 16 KB: Ws quarter | Wt quarter

    const int wave = threadIdx.x >> 6, lane = threadIdx.x & 63;
    const int rsub = lane & 15;
    const int ksub = (lane >> 4) * 8;
    const int csub = (lane >> 4) * 4;

    const int h = blockIdx.x & 3;  // column quarter (gridDim.x % 4 == 0)

    // stage quarter of Ws and quarter of Wt: 1024 frag-rows of 8 ushorts
    for (int i = threadIdx.x; i < 1024; i += 256) {
        int wsel = i >> 9;              // 0 = Ws, 1 = Wt
        int rem = i & 511;              // kk(2b) | ntl(1b) | lane(6b)
        int kk = rem >> 7;
        int ntl = (rem >> 6) & 1;
        int ln = rem & 63;
        int gfrag = (kk * 8 + h * 2 + ntl) * 64 + ln;
        *(ushort8v*)&lds[(size_t)i * 8] =
            *(const ushort8v*)&Wpk[((size_t)wsel * 16384) + (size_t)gfrag * 8];
    }
    __syncthreads();
    const unsigned short* wsf = lds;           // 512 frag-rows
    const unsigned short* wtf = lds + 4096;    // 512 frag-rows

    for (int idx = blockIdx.x; idx < nidx; idx += gridDim.x) {
        const int tile = idx >> 2;     // idx&3 == h (gridDim.x multiple of 4)
        const int m = tile * 64 + wave * 16 + rsub;
        const int mld = (m < N) ? m : (N - 1);
        const bool valid = (m < N);

        bf16x8 af[4];
#pragma unroll
        for (int kk = 0; kk < 4; ++kk)
            af[kk] = *(const bf16x8*)&Ab[(size_t)mld * DIMS + kk * 32 + ksub];

        f32x4 acc_s[2], acc_t[2];
#pragma unroll
        for (int nt = 0; nt < 2; ++nt) {
            acc_s[nt] = (f32x4){0.f, 0.f, 0.f, 0.f};
            acc_t[nt] = (f32x4){0.f, 0.f, 0.f, 0.f};
        }

#pragma unroll
        for (int kk = 0; kk < 4; ++kk) {
#pragma unroll
            for (int nt = 0; nt < 2; ++nt) {
                const int fi = ((kk * 2 + nt) * 64 + lane) * 8;
                bf16x8 ws = *(const bf16x8*)&wsf[fi];
                bf16x8 wt = *(const bf16x8*)&wtf[fi];
                acc_s[nt] = __builtin_amdgcn_mfma_f32_16x16x32_bf16(ws, af[kk], acc_s[nt], 0, 0, 0);
                acc_t[nt] = __builtin_amdgcn_mfma_f32_16x16x32_bf16(wt, af[kk], acc_t[nt], 0, 0, 0);
            }
        }

        if (valid) {
#pragma unroll
            for (int nt = 0; nt < 2; ++nt) {
                const int c4 = (h * 2 + nt) * 16 + csub;
                float4 bsv = *(const float4*)&bs[c4];
                float4 btv = *(const float4*)&bt[c4];
                float4 xo  = *(const float4*)&Xo[(size_t)m * DIMS + c4];
                float4 o;
                o.x = xo.x * expf(tanhf(acc_s[nt][0] + bsv.x)) + (acc_t[nt][0] + btv.x);
                o.y = xo.y * expf(tanhf(acc_s[nt][1] + bsv.y)) + (acc_t[nt][1] + btv.y);
                o.z = xo.z * expf(tanhf(acc_s[nt][2] + bsv.z)) + (acc_t[nt][2] + btv.z);
                o.w = xo.w * expf(tanhf(acc_s[nt][3] + bsv.w)) + (acc_t[nt][3] + btv.w);
                *(float4*)&Out[(size_t)m * DIMS + c4] = o;
                if (Out8) {
                    *(unsigned int*)&Out8[(size_t)m * DIMS + c4] =
                        fp8x4_pack(o.x, o.y, o.z, o.w);
                }
            }
        }
    }
}

// ---------------- f32 fallback kernels ----------------
__global__ void k_fill(const int* __restrict__ src, const int* __restrict__ dst,
                       const int* __restrict__ row_ptr, int* __restrict__ cursor,
                       const float* __restrict__ dinv,
                       int* __restrict__ col, float* __restrict__ wgt, int E) {
    int e = blockIdx.x * blockDim.x + threadIdx.x;
    if (e >= E) return;
    int s = src[e], d = dst[e];
    int pos = row_ptr[d] + atomicAdd(&cursor[d], 1);
    col[pos] = s;
    wgt[pos] = dinv[s] * dinv[d];
}

__global__ __launch_bounds__(256) void k_gather(
    const float4* __restrict__ X4, const float* __restrict__ dinv,
    const int* __restrict__ row_ptr, const int* __restrict__ cnt,
    const int* __restrict__ col, const float* __restrict__ wgt,
    float4* __restrict__ agg4, int N)
{
    int t = blockIdx.x * blockDim.x + threadIdx.x;
    int node = t >> 5;
    if (node >= N) return;
    int lane = t & 31;
    float ds = dinv[node];
    float w0 = ds * ds;
    float4 acc = X4[(size_t)node * 32 + lane];
    acc.x *= w0; acc.y *= w0; acc.z *= w0; acc.w *= w0;
    int beg = row_ptr[node];
    int m = cnt[node];
    for (int j = 0; j < m; ++j) {
        int s0 = col[beg + j];
        float wa = wgt[beg + j];
        float4 v0 = X4[(size_t)s0 * 32 + lane];
        acc.x = fmaf(wa, v0.x, acc.x); acc.y = fmaf(wa, v0.y, acc.y);
        acc.z = fmaf(wa, v0.z, acc.z); acc.w = fmaf(wa, v0.w, acc.w);
    }
    agg4[(size_t)node * 32 + lane] = acc;
}

__global__ __launch_bounds__(256) void k_gemm_couple(
    const float* A, const float* __restrict__ Ws, const float* __restrict__ bs,
    const float* __restrict__ Wt, const float* __restrict__ bt,
    const float* __restrict__ Xo, float* Out, int N)
{
    constexpr int TM = 64, TK = 16;
    __shared__ float As[TK][TM + 4];
    __shared__ float Ss[TK][DIMS];
    __shared__ float St[TK][DIMS];
    const int tid = threadIdx.x;
    const int ty = tid >> 4, tx = tid & 15;
    const int r0 = ty * 4, c0 = tx * 8;
    const int block_row = blockIdx.x * TM;

    float acc_s[4][8], acc_t[4][8];
#pragma unroll
    for (int r = 0; r < 4; ++r)
#pragma unroll
        for (int c = 0; c < 8; ++c) { acc_s[r][c] = 0.f; acc_t[r][c] = 0.f; }

    const int ar = tid >> 2;
    const int aq = tid & 3;
    int arow = block_row + ar;
    if (arow >= N) arow = N - 1;

    for (int k0 = 0; k0 < DIMS; k0 += TK) {
        __syncthreads();
        {
            float4 v = *(const float4*)&A[(size_t)arow * DIMS + k0 + aq * 4];
            As[aq * 4 + 0][ar] = v.x;
            As[aq * 4 + 1][ar] = v.y;
            As[aq * 4 + 2][ar] = v.z;
            As[aq * 4 + 3][ar] = v.w;
        }
#pragma unroll
        for (int i = 0; i < 2; ++i) {
            int idx = tid + i * 256;
            int kk = idx >> 5;
            int j4 = idx & 31;
            *(float4*)&Ss[kk][j4 * 4] = *(const float4*)&Ws[(size_t)(k0 + kk) * DIMS + j4 * 4];
            *(float4*)&St[kk][j4 * 4] = *(const float4*)&Wt[(size_t)(k0 + kk) * DIMS + j4 * 4];
        }
        __syncthreads();
#pragma unroll
        for (int k = 0; k < TK; ++k) {
            float4 av = *(const float4*)&As[k][r0];
            float a[4] = {av.x, av.y, av.z, av.w};
            float ws8[8], wt8[8];
            *(float4*)&ws8[0] = *(const float4*)&Ss[k][c0];
            *(float4*)&ws8[4] = *(const float4*)&Ss[k][c0 + 4];
            *(float4*)&wt8[0] = *(const float4*)&St[k][c0];
            *(float4*)&wt8[4] = *(const float4*)&St[k][c0 + 4];
#pragma unroll
            for (int r = 0; r < 4; ++r)
#pragma unroll
                for (int c = 0; c < 8; ++c) {
                    acc_s[r][c] = fmaf(a[r], ws8[c], acc_s[r][c]);
                    acc_t[r][c] = fmaf(a[r], wt8[c], acc_t[r][c]);
                }
        }
    }

    float bsv[8], btv[8];
    *(float4*)&bsv[0] = *(const float4*)&bs[c0];
    *(float4*)&bsv[4] = *(const float4*)&bs[c0 + 4];
    *(float4*)&btv[0] = *(const float4*)&bt[c0];
    *(float4*)&btv[4] = *(const float4*)&bt[c0 + 4];
#pragma unroll
    for (int r = 0; r < 4; ++r) {
        int row = block_row + r0 + r;
        if (row < N) {
            float xo[8];
            *(float4*)&xo[0] = *(const float4*)&Xo[(size_t)row * DIMS + c0];
            *(float4*)&xo[4] = *(const float4*)&Xo[(size_t)row * DIMS + c0 + 4];
            float o[8];
#pragma unroll
            for (int c = 0; c < 8; ++c) {
                float s = tanhf(acc_s[r][c] + bsv[c]);
                float t = acc_t[r][c] + btv[c];
                o[c] = xo[c] * expf(s) + t;
            }
            *(float4*)&Out[(size_t)row * DIMS + c0] = *(const float4*)&o[0];
            *(float4*)&Out[(size_t)row * DIMS + c0 + 4] = *(const float4*)&o[4];
        }
    }
}

extern "C" void kernel_launch(void* const* d_in, const int* in_sizes, int n_in,
                              void* d_out, int out_size, void* d_ws, size_t ws_size,
                              hipStream_t stream) {
    const float* x_main  = (const float*)d_in[0];
    const float* x_guide = (const float*)d_in[1];
    const int*   ei      = (const int*)d_in[2];
    const float* Ws1 = (const float*)d_in[3];
    const float* bs1 = (const float*)d_in[4];
    const float* Wt1 = (const float*)d_in[5];
    const float* bt1 = (const float*)d_in[6];
    const float* Ws2 = (const float*)d_in[7];
    const float* bs2 = (const float*)d_in[8];
    const float* Wt2 = (const float*)d_in[9];
    const float* bt2 = (const float*)d_in[10];

    const int N = in_sizes[0] / DIMS;
    const int E = in_sizes[2] / 2;
    const int* src = ei;
    const int* dst = ei + E;

    float* out_main  = (float*)d_out;
    float* out_guide = out_main + (size_t)N * DIMS;

    // ---- ws layout ----
    char* w = (char*)d_ws;
    size_t off = 0;
    auto alloc = [&](size_t bytes) { size_t o = off; off = (off + bytes + 15) & ~(size_t)15; return o; };
    int*   cnt      = (int*)(w + alloc((size_t)N * 4));
    int*   row_ptr  = (int*)(w + alloc((size_t)N * 4));
    int*   bump     = (int*)(w + alloc(64));
    int*   bktCnt    = (int*)(w + alloc(512 * 16 * 4));
    int*   bktCursor = (int*)(w + alloc(512 * 16 * 4));
    int*   bktBase   = (int*)(w + alloc(513 * 4));
    float* dinv     = (float*)(w + alloc((size_t)N * 4));
    int*   col      = (int*)(w + alloc((size_t)E * 4));
    size_t base_end = off;
    unsigned char*  xq   = (unsigned char*)(w + alloc((size_t)N * DIMS));
    unsigned short* aggb = (unsigned short*)(w + alloc((size_t)N * DIMS * 2));
    unsigned short* wpk  = (unsigned short*)(w + alloc((size_t)4 * 16384 * 2));
    size_t needed_fp8 = off;
    int*          slot = (int*)aggb;
    unsigned int* epk  = (unsigned int*)aggb;
    int*   cursor_fb = (int*)(w + base_end);
    float* wgt_fb    = (float*)(w + base_end + (((size_t)N * 4 + 15) & ~(size_t)15));
    size_t needed_f32 = base_end + ((size_t)N * 4 + 16) + (size_t)E * 4;

    const int gemm_grid  = (N + 63) / 64;
    const int ntiles64   = (N + 63) / 64;
    const int nidx       = ntiles64 * 4;   // quarter-column blocks
    int mfma_grid        = (nidx < 2048) ? nidx : 2048;
    mfma_grid            = (mfma_grid + 3) & ~3;   // multiple of 4 so h is loop-invariant

    const int nbkt = (N + 511) >> 9;
    const bool bucketed_ok = (nbkt <= 512) && (N < (1 << 23)) &&
                             ((size_t)E * 4 <= (size_t)N * DIMS * 2);

    if (ws_size >= needed_fp8) {
        // ---- CSR build ----
        if (bucketed_ok) {
            const int Ec = (E + 255) / 256;
            hipMemsetAsync(bktCnt, 0, (size_t)nbkt * 16 * 4, stream);
            k_bhist<<<256, 1024, 0, stream>>>(dst, bktCnt, E, nbkt, Ec);
            k_bscan<<<1, 64, 0, stream>>>(bktCnt, bktBase, bktCursor, nbkt, E);
            k_bscatter<<<256, 1024, 0, stream>>>(src, dst, bktCursor, epk, E, nbkt, Ec);
            k_bcsr<<<nbkt, 512, 0, stream>>>(epk, bktBase, col, row_ptr, cnt, dinv, N);
        } else {
            hipMemsetAsync(cnt, 0, (size_t)N * 4, stream);
            hipMemsetAsync(bump, 0, 64, stream);
            k_count_slot<<<(E + 255) / 256, 256, 0, stream>>>(dst, cnt, slot, E);
            k_alloc<<<(N + 255) / 256, 256, 0, stream>>>(cnt, row_ptr, bump, N);
            k_fill3<<<(E + 255) / 256, 256, 0, stream>>>(src, dst, row_ptr, slot, col, E);
            k_dinv2<<<(N + 255) / 256, 256, 0, stream>>>(cnt, dinv, N);
        }

        k_wpack4<<<dim3(8, 4), 256, 0, stream>>>(Ws1, Wt1, Ws2, Wt2, wpk);
        unsigned short* W1pk = wpk;
        unsigned short* W2pk = wpk + 2 * 16384;

        const int n8 = N * DIMS / 8;
        k_cast_q<<<(n8 + 255) / 256, 256, 0, stream>>>(x_guide, xq, n8);

        const int gather_grid = (N * 16 + 255) / 256;
        // ---- stage 1: neighbors fp8(x_guide), self f32 x_guide ----
        k_gather_q2<<<gather_grid, 256, 0, stream>>>(xq, x_guide, dinv, row_ptr, cnt, col, aggb, N);
        k_mfma_couple6<<<mfma_grid, 256, 0, stream>>>(aggb, W1pk, bs1, bt1, x_main,
                                                      out_main, xq, N, nidx);
        // ---- stage 2: neighbors fp8(out_main), self f32 out_main ----
        k_gather_q2<<<gather_grid, 256, 0, stream>>>(xq, out_main, dinv, row_ptr, cnt, col, aggb, N);
        k_mfma_couple6<<<mfma_grid, 256, 0, stream>>>(aggb, W2pk, bs2, bt2, x_guide,
                                                      out_guide, nullptr, N, nidx);
    } else if (ws_size >= needed_f32) {
        float* agg = out_guide;
        hipMemsetAsync(cnt, 0, (size_t)N * 4, stream);
        hipMemsetAsync(bump, 0, 64, stream);
        hipMemsetAsync(cursor_fb, 0, (size_t)N * 4, stream);
        k_count_slot<<<(E + 255) / 256, 256, 0, stream>>>(dst, cnt, col, E);
        k_dinv2<<<(N + 255) / 256, 256, 0, stream>>>(cnt, dinv, N);
        k_alloc<<<(N + 255) / 256, 256, 0, stream>>>(cnt, row_ptr, bump, N);
        k_fill<<<(E + 255) / 256, 256, 0, stream>>>(src, dst, row_ptr, cursor_fb, dinv, col, wgt_fb, E);
        const int gather_grid32 = (N * 32 + 255) / 256;
        k_gather<<<gather_grid32, 256, 0, stream>>>((const float4*)x_guide, dinv, row_ptr, cnt,
                                                    col, wgt_fb, (float4*)agg, N);
        k_gemm_couple<<<gemm_grid, 256, 0, stream>>>(agg, Ws1, bs1, Wt1, bt1, x_main, out_main, N);
        k_gather<<<gather_grid32, 256, 0, stream>>>((const float4*)out_main, dinv, row_ptr, cnt,
                                                    col, wgt_fb, (float4*)agg, N);
        k_gemm_couple<<<gemm_grid, 256, 0, stream>>>(agg, Ws2, bs2, Wt2, bt2, x_guide, out_guide, N);
    }
}

// Round 17
// 280.969 us; speedup vs baseline: 1.0104x; 1.0104x over previous
//
#include <hip/hip_runtime.h>
#include <cstdint>
#include <cstddef>

constexpr int DIMS = 128;

typedef __attribute__((ext_vector_type(8))) short bf16x8;
typedef __attribute__((ext_vector_type(8))) unsigned short ushort8v;
typedef __attribute__((ext_vector_type(4))) float f32x4;
typedef __attribute__((ext_vector_type(2))) float f32x2;

#if defined(__has_builtin)
# if __has_builtin(__builtin_amdgcn_cvt_pk_f32_fp8) && __has_builtin(__builtin_amdgcn_cvt_pk_fp8_f32)
#  define FP8_HW 1
# endif
#endif
#ifndef FP8_HW
# define FP8_HW 0
#endif

__device__ __forceinline__ unsigned short f2b(float f) {
    uint32_t u = __builtin_bit_cast(uint32_t, f);
    uint32_t r = (u + 0x7FFFu + ((u >> 16) & 1u)) >> 16;
    return (unsigned short)r;
}
__device__ __forceinline__ float b2f(unsigned short h) {
    uint32_t u = ((uint32_t)h) << 16;
    return __builtin_bit_cast(float, u);
}

// ---- fp8 e4m3fn helpers ----
__device__ __forceinline__ float q2f_sw(unsigned char v) {
    uint32_t em = v & 0x7fu;
    float mag;
    if (em >= 0x08u) {
        uint32_t bits = (((em >> 3) + 120u) << 23) | ((em & 7u) << 20);
        mag = __builtin_bit_cast(float, bits);
    } else {
        mag = (float)em * 0.001953125f;
    }
    return (v & 0x80u) ? -mag : mag;
}
__device__ __forceinline__ unsigned char f2q_sw(float f) {
    uint32_t u = __builtin_bit_cast(uint32_t, f);
    uint32_t s = (u >> 24) & 0x80u;
    int e = (int)((u >> 23) & 0xffu) - 127;
    uint32_t m = u & 0x7fffffu;
    if (e < -9) return (unsigned char)s;
    if (e > 8) return (unsigned char)(s | 0x7eu);
    if (e >= -6) {
        uint32_t mant = m >> 20;
        uint32_t rem = m & 0xfffffu;
        uint32_t r = mant + ((rem > 0x80000u) || (rem == 0x80000u && (mant & 1u)));
        uint32_t v = (((uint32_t)(e + 7)) << 3) + r;
        if (v >= 0x7fu) v = 0x7eu;
        return (unsigned char)(s | v);
    }
    float scaled = fabsf(f) * 512.0f;
    int q = (int)(scaled + 0.5f);
    if (q > 8) q = 8;
    return (unsigned char)(s | (uint32_t)q);
}

__device__ __forceinline__ void fp8x8_fma(uint2 v, float w, float* acc) {
#if FP8_HW
    f32x2 a0 = __builtin_amdgcn_cvt_pk_f32_fp8((int)v.x, false);
    f32x2 a1 = __builtin_amdgcn_cvt_pk_f32_fp8((int)v.x, true);
    f32x2 a2 = __builtin_amdgcn_cvt_pk_f32_fp8((int)v.y, false);
    f32x2 a3 = __builtin_amdgcn_cvt_pk_f32_fp8((int)v.y, true);
    acc[0] = fmaf(w, a0[0], acc[0]); acc[1] = fmaf(w, a0[1], acc[1]);
    acc[2] = fmaf(w, a1[0], acc[2]); acc[3] = fmaf(w, a1[1], acc[3]);
    acc[4] = fmaf(w, a2[0], acc[4]); acc[5] = fmaf(w, a2[1], acc[5]);
    acc[6] = fmaf(w, a3[0], acc[6]); acc[7] = fmaf(w, a3[1], acc[7]);
#else
#pragma unroll
    for (int q = 0; q < 8; ++q) {
        unsigned char b = (unsigned char)(((q < 4 ? v.x : v.y) >> ((q & 3) * 8)) & 0xffu);
        acc[q] = fmaf(w, q2f_sw(b), acc[q]);
    }
#endif
}

__device__ __forceinline__ unsigned int fp8x4_pack(float a, float b, float c, float d) {
#if FP8_HW
    int r = 0;
    r = __builtin_amdgcn_cvt_pk_fp8_f32(a, b, r, false);
    r = __builtin_amdgcn_cvt_pk_fp8_f32(c, d, r, true);
    return (unsigned int)r;
#else
    return (unsigned int)f2q_sw(a) | ((unsigned int)f2q_sw(b) << 8) |
           ((unsigned int)f2q_sw(c) << 16) | ((unsigned int)f2q_sw(d) << 24);
#endif
}

// ================= bucketed CSR build =================
__global__ __launch_bounds__(1024) void k_bhist(const int* __restrict__ dst,
                                                int* __restrict__ bktCnt,
                                                int E, int nbkt, int Ec) {
    __shared__ int lh[512];
    if (threadIdx.x < 512) lh[threadIdx.x] = 0;
    __syncthreads();
    int base = blockIdx.x * Ec;
    int end = min(E, base + Ec);
    for (int i = base + threadIdx.x; i < end; i += 1024)
        atomicAdd(&lh[dst[i] >> 9], 1);
    __syncthreads();
    if (threadIdx.x < nbkt) {
        int v = lh[threadIdx.x];
        if (v) atomicAdd(&bktCnt[threadIdx.x * 16], v);
    }
}

__global__ void k_bscan(const int* __restrict__ bktCnt, int* __restrict__ bktBase,
                        int* __restrict__ bktCursor, int nbkt, int E) {
    int lane = threadIdx.x;  // blockDim.x == 64
    int v[8]; int s = 0;
#pragma unroll
    for (int k = 0; k < 8; ++k) {
        int idx = lane * 8 + k;
        int c = (idx < nbkt) ? bktCnt[idx * 16] : 0;
        v[k] = s; s += c;
    }
    int x = s;
#pragma unroll
    for (int d = 1; d < 64; d <<= 1) {
        int y = __shfl_up(x, d);
        if (lane >= d) x += y;
    }
    int excl = x - s;
#pragma unroll
    for (int k = 0; k < 8; ++k) {
        int idx = lane * 8 + k;
        if (idx < nbkt) { int bb = excl + v[k]; bktBase[idx] = bb; bktCursor[idx * 16] = bb; }
    }
    if (lane == 0) bktBase[nbkt] = E;
}

__global__ __launch_bounds__(1024) void k_bscatter(const int* __restrict__ src,
                                                   const int* __restrict__ dst,
                                                   int* __restrict__ bktCursor,
                                                   unsigned int* __restrict__ epk,
                                                   int E, int nbkt, int Ec) {
    __shared__ int lh[512];
    __shared__ int lbase[512];
    __shared__ int lcur[512];
    if (threadIdx.x < 512) { lh[threadIdx.x] = 0; lcur[threadIdx.x] = 0; }
    __syncthreads();
    int base = blockIdx.x * Ec;
    int end = min(E, base + Ec);
    for (int i = base + threadIdx.x; i < end; i += 1024)
        atomicAdd(&lh[dst[i] >> 9], 1);
    __syncthreads();
    if (threadIdx.x < nbkt) {
        int c = lh[threadIdx.x];
        lbase[threadIdx.x] = c ? atomicAdd(&bktCursor[threadIdx.x * 16], c) : 0;
    }
    __syncthreads();
    for (int i = base + threadIdx.x; i < end; i += 1024) {
        int d = dst[i], s = src[i];
        int b = d >> 9;
        int r = atomicAdd(&lcur[b], 1);
        epk[lbase[b] + r] = ((unsigned int)s << 9) | (unsigned int)(d & 511);
    }
}

__global__ __launch_bounds__(512) void k_bcsr(const unsigned int* __restrict__ epk,
                                              const int* __restrict__ bktBase,
                                              int* __restrict__ col, int* __restrict__ row_ptr,
                                              int* __restrict__ cnt, float* __restrict__ dinv,
                                              int N) {
    __shared__ int lcnt[512];
    __shared__ int loff[512];
    __shared__ int lcur[512];
    const int b = blockIdx.x;
    const int node0 = b << 9;
    lcnt[threadIdx.x] = 0; lcur[threadIdx.x] = 0;
    __syncthreads();
    const int ebeg = bktBase[b], eend = bktBase[b + 1];
    for (int i = ebeg + threadIdx.x; i < eend; i += 512)
        atomicAdd(&lcnt[epk[i] & 511u], 1);
    __syncthreads();
    if (threadIdx.x < 64) {
        int lane = threadIdx.x;
        int v[8]; int s = 0;
#pragma unroll
        for (int k = 0; k < 8; ++k) { v[k] = s; s += lcnt[lane * 8 + k]; }
        int x = s;
#pragma unroll
        for (int d = 1; d < 64; d <<= 1) { int y = __shfl_up(x, d); if (lane >= d) x += y; }
        int excl = x - s;
#pragma unroll
        for (int k = 0; k < 8; ++k) loff[lane * 8 + k] = excl + v[k];
    }
    __syncthreads();
    const int node = node0 + threadIdx.x;
    if (node < N) {
        int c = lcnt[threadIdx.x];
        row_ptr[node] = ebeg + loff[threadIdx.x];
        cnt[node] = c;
        dinv[node] = rsqrtf((float)(c + 1));
    }
    for (int i = ebeg + threadIdx.x; i < eend; i += 512) {
        unsigned int e = epk[i];
        int dl = e & 511u;
        int r = atomicAdd(&lcur[dl], 1);
        col[ebeg + loff[dl] + r] = (int)(e >> 9);
    }
}

// ================= old-path CSR kernels (fallback when nbkt > 512) =================
__global__ void k_count_slot(const int* __restrict__ dst, int* __restrict__ cnt,
                             int* __restrict__ slot, int E) {
    int e = blockIdx.x * blockDim.x + threadIdx.x;
    if (e < E) slot[e] = atomicAdd(&cnt[dst[e]], 1);
}

__global__ void k_alloc(const int* __restrict__ cnt, int* __restrict__ row_ptr,
                        int* __restrict__ bump, int N) {
    int i = blockIdx.x * blockDim.x + threadIdx.x;
    int lane = threadIdx.x & 63;
    int v = (i < N) ? cnt[i] : 0;
    int x = v;
#pragma unroll
    for (int d = 1; d < 64; d <<= 1) {
        int y = __shfl_up(x, d);
        if (lane >= d) x += y;
    }
    int total = __shfl(x, 63);
    int base = 0;
    if (lane == 0) base = atomicAdd(bump, total);
    base = __shfl(base, 0);
    if (i < N) row_ptr[i] = base + x - v;
}

__global__ void k_fill3(const int* __restrict__ src, const int* __restrict__ dst,
                        const int* __restrict__ row_ptr, const int* __restrict__ slot,
                        int* __restrict__ col, int E) {
    int e = blockIdx.x * blockDim.x + threadIdx.x;
    if (e >= E) return;
    col[row_ptr[dst[e]] + slot[e]] = src[e];
}

__global__ void k_dinv2(const int* __restrict__ cnt, float* __restrict__ dinv, int N) {
    int i = blockIdx.x * blockDim.x + threadIdx.x;
    if (i < N) dinv[i] = rsqrtf((float)(cnt[i] + 1));
}

// ---------------- f32 -> fp8 cast ----------------
__global__ void k_cast_q(const float* __restrict__ X, unsigned char* __restrict__ Yq, int n8) {
    int i = blockIdx.x * blockDim.x + threadIdx.x;
    if (i >= n8) return;
    const float4* p = (const float4*)X + (size_t)i * 2;
    float4 a = p[0], b = p[1];
    uint2 q;
    q.x = fp8x4_pack(a.x, a.y, a.z, a.w);
    q.y = fp8x4_pack(b.x, b.y, b.z, b.w);
    *(uint2*)&Yq[(size_t)i * 8] = q;
}

__global__ void k_wpack4(const float* __restrict__ W0, const float* __restrict__ W1,
                         const float* __restrict__ W2, const float* __restrict__ W3,
                         unsigned short* __restrict__ out) {
    int t = blockIdx.x * blockDim.x + threadIdx.x;  // 0..2047
    if (t >= 2048) return;
    const float* W = (blockIdx.y == 0) ? W0 : (blockIdx.y == 1) ? W1
                   : (blockIdx.y == 2) ? W2 : W3;
    unsigned short* o = out + (size_t)blockIdx.y * 16384;
    int lane = t & 63;
    int nt = (t >> 6) & 7;
    int kk = t >> 9;
    int n = nt * 16 + (lane & 15);
    int k0 = kk * 32 + (lane >> 4) * 8;
    ushort8v h8;
#pragma unroll
    for (int j = 0; j < 8; ++j) h8[j] = f2b(W[(size_t)(k0 + j) * DIMS + n]);
    *(ushort8v*)&o[(size_t)t * 8] = h8;
}

// ---------------- gather: fp8 neighbors + f32 self, f32 accum, bf16 out ----------------
__global__ __launch_bounds__(256) void k_gather_q2(
    const unsigned char* __restrict__ Xq, const float* __restrict__ Xf,
    const float* __restrict__ dinv,
    const int* __restrict__ row_ptr, const int* __restrict__ cnt,
    const int* __restrict__ col, unsigned short* __restrict__ aggb, int N)
{
    int t = blockIdx.x * blockDim.x + threadIdx.x;
    int node = t >> 4;
    if (node >= N) return;
    const size_t base = (size_t)(t & 15) * 8;

    float ds = dinv[node];
    float w0 = ds * ds;
    const float4* sp = (const float4*)&Xf[(size_t)node * DIMS + base];
    float4 s0v = sp[0], s1v = sp[1];
    float acc[8];
    acc[0] = s0v.x * w0; acc[1] = s0v.y * w0; acc[2] = s0v.z * w0; acc[3] = s0v.w * w0;
    acc[4] = s1v.x * w0; acc[5] = s1v.y * w0; acc[6] = s1v.z * w0; acc[7] = s1v.w * w0;

    const int beg = row_ptr[node];
    const int m = cnt[node];
    int j = 0;
    for (; j + 1 < m; j += 2) {
        int n0 = col[beg + j], n1 = col[beg + j + 1];
        float wa = ds * dinv[n0], wb = ds * dinv[n1];
        uint2 v0 = *(const uint2*)&Xq[(size_t)n0 * DIMS + base];
        uint2 v1 = *(const uint2*)&Xq[(size_t)n1 * DIMS + base];
        fp8x8_fma(v0, wa, acc);
        fp8x8_fma(v1, wb, acc);
    }
    if (j < m) {
        int n0 = col[beg + j];
        float wa = ds * dinv[n0];
        uint2 v0 = *(const uint2*)&Xq[(size_t)n0 * DIMS + base];
        fp8x8_fma(v0, wa, acc);
    }
    ushort8v o;
#pragma unroll
    for (int q = 0; q < 8; ++q) o[q] = f2b(acc[q]);
    *(ushort8v*)&aggb[(size_t)node * DIMS + base] = o;
}

// ---------------- MFMA dual-GEMM + coupling, v7: 512 thr, 128 rows x 64 cols, 32KB LDS ----------------
// Same per-wave work as couple5; 8 waves/block -> 4 blocks/CU -> 32 waves/CU.
__global__ __launch_bounds__(512) void k_mfma_couple7(
    const unsigned short* __restrict__ Ab, const unsigned short* __restrict__ Wpk,
    const float* __restrict__ bs, const float* __restrict__ bt,
    const float* __restrict__ Xo, float* __restrict__ Out,
    unsigned char* Out8, int N, int nidx)
{
    __shared__ unsigned short lds[16384];  // 32 KB: Ws half | Wt half

    const int wave = threadIdx.x >> 6, lane = threadIdx.x & 63;
    const int rsub = lane & 15;
    const int ksub = (lane >> 4) * 8;
    const int csub = (lane >> 4) * 4;

    const int h = blockIdx.x & 1;  // column half (gridDim.x even)

    for (int i = threadIdx.x; i < 2048; i += 512) {
        int wsel = i >> 10;
        int rem = i & 1023;
        int kk = rem >> 8;
        int ntl = (rem >> 6) & 3;
        int ln = rem & 63;
        int gfrag = (kk * 8 + h * 4 + ntl) * 64 + ln;
        *(ushort8v*)&lds[(size_t)i * 8] =
            *(const ushort8v*)&Wpk[((size_t)wsel * 16384) + (size_t)gfrag * 8];
    }
    __syncthreads();
    const unsigned short* wsf = lds;
    const unsigned short* wtf = lds + 8192;

    for (int idx = blockIdx.x; idx < nidx; idx += gridDim.x) {
        const int tile = idx >> 1;     // idx&1 == h
        const int m = tile * 128 + wave * 16 + rsub;
        const int mld = (m < N) ? m : (N - 1);
        const bool valid = (m < N);

        bf16x8 af[4];
#pragma unroll
        for (int kk = 0; kk < 4; ++kk)
            af[kk] = *(const bf16x8*)&Ab[(size_t)mld * DIMS + kk * 32 + ksub];

        f32x4 acc_s[4], acc_t[4];
#pragma unroll
        for (int nt = 0; nt < 4; ++nt) {
            acc_s[nt] = (f32x4){0.f, 0.f, 0.f, 0.f};
            acc_t[nt] = (f32x4){0.f, 0.f, 0.f, 0.f};
        }

#pragma unroll
        for (int kk = 0; kk < 4; ++kk) {
#pragma unroll
            for (int nt = 0; nt < 4; ++nt) {
                const int fi = ((kk * 4 + nt) * 64 + lane) * 8;
                bf16x8 ws = *(const bf16x8*)&wsf[fi];
                bf16x8 wt = *(const bf16x8*)&wtf[fi];
                acc_s[nt] = __builtin_amdgcn_mfma_f32_16x16x32_bf16(ws, af[kk], acc_s[nt], 0, 0, 0);
                acc_t[nt] = __builtin_amdgcn_mfma_f32_16x16x32_bf16(wt, af[kk], acc_t[nt], 0, 0, 0);
            }
        }

        if (valid) {
#pragma unroll
            for (int nt = 0; nt < 4; ++nt) {
                const int c4 = (h * 4 + nt) * 16 + csub;
                float4 bsv = *(const float4*)&bs[c4];
                float4 btv = *(const float4*)&bt[c4];
                float4 xo  = *(const float4*)&Xo[(size_t)m * DIMS + c4];
                float4 o;
                o.x = xo.x * expf(tanhf(acc_s[nt][0] + bsv.x)) + (acc_t[nt][0] + btv.x);
                o.y = xo.y * expf(tanhf(acc_s[nt][1] + bsv.y)) + (acc_t[nt][1] + btv.y);
                o.z = xo.z * expf(tanhf(acc_s[nt][2] + bsv.z)) + (acc_t[nt][2] + btv.z);
                o.w = xo.w * expf(tanhf(acc_s[nt][3] + bsv.w)) + (acc_t[nt][3] + btv.w);
                *(float4*)&Out[(size_t)m * DIMS + c4] = o;
                if (Out8) {
                    *(unsigned int*)&Out8[(size_t)m * DIMS + c4] =
                        fp8x4_pack(o.x, o.y, o.z, o.w);
                }
            }
        }
    }
}

// ---------------- f32 fallback kernels ----------------
__global__ void k_fill(const int* __restrict__ src, const int* __restrict__ dst,
                       const int* __restrict__ row_ptr, int* __restrict__ cursor,
                       const float* __restrict__ dinv,
                       int* __restrict__ col, float* __restrict__ wgt, int E) {
    int e = blockIdx.x * blockDim.x + threadIdx.x;
    if (e >= E) return;
    int s = src[e], d = dst[e];
    int pos = row_ptr[d] + atomicAdd(&cursor[d], 1);
    col[pos] = s;
    wgt[pos] = dinv[s] * dinv[d];
}

__global__ __launch_bounds__(256) void k_gather(
    const float4* __restrict__ X4, const float* __restrict__ dinv,
    const int* __restrict__ row_ptr, const int* __restrict__ cnt,
    const int* __restrict__ col, const float* __restrict__ wgt,
    float4* __restrict__ agg4, int N)
{
    int t = blockIdx.x * blockDim.x + threadIdx.x;
    int node = t >> 5;
    if (node >= N) return;
    int lane = t & 31;
    float ds = dinv[node];
    float w0 = ds * ds;
    float4 acc = X4[(size_t)node * 32 + lane];
    acc.x *= w0; acc.y *= w0; acc.z *= w0; acc.w *= w0;
    int beg = row_ptr[node];
    int m = cnt[node];
    for (int j = 0; j < m; ++j) {
        int s0 = col[beg + j];
        float wa = wgt[beg + j];
        float4 v0 = X4[(size_t)s0 * 32 + lane];
        acc.x = fmaf(wa, v0.x, acc.x); acc.y = fmaf(wa, v0.y, acc.y);
        acc.z = fmaf(wa, v0.z, acc.z); acc.w = fmaf(wa, v0.w, acc.w);
    }
    agg4[(size_t)node * 32 + lane] = acc;
}

__global__ __launch_bounds__(256) void k_gemm_couple(
    const float* A, const float* __restrict__ Ws, const float* __restrict__ bs,
    const float* __restrict__ Wt, const float* __restrict__ bt,
    const float* __restrict__ Xo, float* Out, int N)
{
    constexpr int TM = 64, TK = 16;
    __shared__ float As[TK][TM + 4];
    __shared__ float Ss[TK][DIMS];
    __shared__ float St[TK][DIMS];
    const int tid = threadIdx.x;
    const int ty = tid >> 4, tx = tid & 15;
    const int r0 = ty * 4, c0 = tx * 8;
    const int block_row = blockIdx.x * TM;

    float acc_s[4][8], acc_t[4][8];
#pragma unroll
    for (int r = 0; r < 4; ++r)
#pragma unroll
        for (int c = 0; c < 8; ++c) { acc_s[r][c] = 0.f; acc_t[r][c] = 0.f; }

    const int ar = tid >> 2;
    const int aq = tid & 3;
    int arow = block_row + ar;
    if (arow >= N) arow = N - 1;

    for (int k0 = 0; k0 < DIMS; k0 += TK) {
        __syncthreads();
        {
            float4 v = *(const float4*)&A[(size_t)arow * DIMS + k0 + aq * 4];
            As[aq * 4 + 0][ar] = v.x;
            As[aq * 4 + 1][ar] = v.y;
            As[aq * 4 + 2][ar] = v.z;
            As[aq * 4 + 3][ar] = v.w;
        }
#pragma unroll
        for (int i = 0; i < 2; ++i) {
            int idx = tid + i * 256;
            int kk = idx >> 5;
            int j4 = idx & 31;
            *(float4*)&Ss[kk][j4 * 4] = *(const float4*)&Ws[(size_t)(k0 + kk) * DIMS + j4 * 4];
            *(float4*)&St[kk][j4 * 4] = *(const float4*)&Wt[(size_t)(k0 + kk) * DIMS + j4 * 4];
        }
        __syncthreads();
#pragma unroll
        for (int k = 0; k < TK; ++k) {
            float4 av = *(const float4*)&As[k][r0];
            float a[4] = {av.x, av.y, av.z, av.w};
            float ws8[8], wt8[8];
            *(float4*)&ws8[0] = *(const float4*)&Ss[k][c0];
            *(float4*)&ws8[4] = *(const float4*)&Ss[k][c0 + 4];
            *(float4*)&wt8[0] = *(const float4*)&St[k][c0];
            *(float4*)&wt8[4] = *(const float4*)&St[k][c0 + 4];
#pragma unroll
            for (int r = 0; r < 4; ++r)
#pragma unroll
                for (int c = 0; c < 8; ++c) {
                    acc_s[r][c] = fmaf(a[r], ws8[c], acc_s[r][c]);
                    acc_t[r][c] = fmaf(a[r], wt8[c], acc_t[r][c]);
                }
        }
    }

    float bsv[8], btv[8];
    *(float4*)&bsv[0] = *(const float4*)&bs[c0];
    *(float4*)&bsv[4] = *(const float4*)&bs[c0 + 4];
    *(float4*)&btv[0] = *(const float4*)&bt[c0];
    *(float4*)&btv[4] = *(const float4*)&bt[c0 + 4];
#pragma unroll
    for (int r = 0; r < 4; ++r) {
        int row = block_row + r0 + r;
        if (row < N) {
            float xo[8];
            *(float4*)&xo[0] = *(const float4*)&Xo[(size_t)row * DIMS + c0];
            *(float4*)&xo[4] = *(const float4*)&Xo[(size_t)row * DIMS + c0 + 4];
            float o[8];
#pragma unroll
            for (int c = 0; c < 8; ++c) {
                float s = tanhf(acc_s[r][c] + bsv[c]);
                float t = acc_t[r][c] + btv[c];
                o[c] = xo[c] * expf(s) + t;
            }
            *(float4*)&Out[(size_t)row * DIMS + c0] = *(const float4*)&o[0];
            *(float4*)&Out[(size_t)row * DIMS + c0 + 4] = *(const float4*)&o[4];
        }
    }
}

extern "C" void kernel_launch(void* const* d_in, const int* in_sizes, int n_in,
                              void* d_out, int out_size, void* d_ws, size_t ws_size,
                              hipStream_t stream) {
    const float* x_main  = (const float*)d_in[0];
    const float* x_guide = (const float*)d_in[1];
    const int*   ei      = (const int*)d_in[2];
    const float* Ws1 = (const float*)d_in[3];
    const float* bs1 = (const float*)d_in[4];
    const float* Wt1 = (const float*)d_in[5];
    const float* bt1 = (const float*)d_in[6];
    const float* Ws2 = (const float*)d_in[7];
    const float* bs2 = (const float*)d_in[8];
    const float* Wt2 = (const float*)d_in[9];
    const float* bt2 = (const float*)d_in[10];

    const int N = in_sizes[0] / DIMS;
    const int E = in_sizes[2] / 2;
    const int* src = ei;
    const int* dst = ei + E;

    float* out_main  = (float*)d_out;
    float* out_guide = out_main + (size_t)N * DIMS;

    // ---- ws layout ----
    char* w = (char*)d_ws;
    size_t off = 0;
    auto alloc = [&](size_t bytes) { size_t o = off; off = (off + bytes + 15) & ~(size_t)15; return o; };
    int*   cnt      = (int*)(w + alloc((size_t)N * 4));
    int*   row_ptr  = (int*)(w + alloc((size_t)N * 4));
    int*   bump     = (int*)(w + alloc(64));
    int*   bktCnt    = (int*)(w + alloc(512 * 16 * 4));
    int*   bktCursor = (int*)(w + alloc(512 * 16 * 4));
    int*   bktBase   = (int*)(w + alloc(513 * 4));
    float* dinv     = (float*)(w + alloc((size_t)N * 4));
    int*   col      = (int*)(w + alloc((size_t)E * 4));
    size_t base_end = off;
    unsigned char*  xq   = (unsigned char*)(w + alloc((size_t)N * DIMS));
    unsigned short* aggb = (unsigned short*)(w + alloc((size_t)N * DIMS * 2));
    unsigned short* wpk  = (unsigned short*)(w + alloc((size_t)4 * 16384 * 2));
    size_t needed_fp8 = off;
    int*          slot = (int*)aggb;
    unsigned int* epk  = (unsigned int*)aggb;
    int*   cursor_fb = (int*)(w + base_end);
    float* wgt_fb    = (float*)(w + base_end + (((size_t)N * 4 + 15) & ~(size_t)15));
    size_t needed_f32 = base_end + ((size_t)N * 4 + 16) + (size_t)E * 4;

    const int gemm_grid  = (N + 63) / 64;
    const int ntiles128  = (N + 127) / 128;
    const int nidx       = ntiles128 * 2;   // half-column blocks, 128-row tiles
    int mfma_grid        = (nidx < 2048) ? nidx : 2048;
    mfma_grid            = (mfma_grid + 1) & ~1;   // even so h is loop-invariant

    const int nbkt = (N + 511) >> 9;
    const bool bucketed_ok = (nbkt <= 512) && (N < (1 << 23)) &&
                             ((size_t)E * 4 <= (size_t)N * DIMS * 2);

    if (ws_size >= needed_fp8) {
        // ---- CSR build ----
        if (bucketed_ok) {
            const int Ec = (E + 255) / 256;
            hipMemsetAsync(bktCnt, 0, (size_t)nbkt * 16 * 4, stream);
            k_bhist<<<256, 1024, 0, stream>>>(dst, bktCnt, E, nbkt, Ec);
            k_bscan<<<1, 64, 0, stream>>>(bktCnt, bktBase, bktCursor, nbkt, E);
            k_bscatter<<<256, 1024, 0, stream>>>(src, dst, bktCursor, epk, E, nbkt, Ec);
            k_bcsr<<<nbkt, 512, 0, stream>>>(epk, bktBase, col, row_ptr, cnt, dinv, N);
        } else {
            hipMemsetAsync(cnt, 0, (size_t)N * 4, stream);
            hipMemsetAsync(bump, 0, 64, stream);
            k_count_slot<<<(E + 255) / 256, 256, 0, stream>>>(dst, cnt, slot, E);
            k_alloc<<<(N + 255) / 256, 256, 0, stream>>>(cnt, row_ptr, bump, N);
            k_fill3<<<(E + 255) / 256, 256, 0, stream>>>(src, dst, row_ptr, slot, col, E);
            k_dinv2<<<(N + 255) / 256, 256, 0, stream>>>(cnt, dinv, N);
        }

        k_wpack4<<<dim3(8, 4), 256, 0, stream>>>(Ws1, Wt1, Ws2, Wt2, wpk);
        unsigned short* W1pk = wpk;
        unsigned short* W2pk = wpk + 2 * 16384;

        const int n8 = N * DIMS / 8;
        k_cast_q<<<(n8 + 255) / 256, 256, 0, stream>>>(x_guide, xq, n8);

        const int gather_grid = (N * 16 + 255) / 256;
        // ---- stage 1: neighbors fp8(x_guide), self f32 x_guide ----
        k_gather_q2<<<gather_grid, 256, 0, stream>>>(xq, x_guide, dinv, row_ptr, cnt, col, aggb, N);
        k_mfma_couple7<<<mfma_grid, 512, 0, stream>>>(aggb, W1pk, bs1, bt1, x_main,
                                                      out_main, xq, N, nidx);
        // ---- stage 2: neighbors fp8(out_main), self f32 out_main ----
        k_gather_q2<<<gather_grid, 256, 0, stream>>>(xq, out_main, dinv, row_ptr, cnt, col, aggb, N);
        k_mfma_couple7<<<mfma_grid, 512, 0, stream>>>(aggb, W2pk, bs2, bt2, x_guide,
                                                      out_guide, nullptr, N, nidx);
    } else if (ws_size >= needed_f32) {
        float* agg = out_guide;
        hipMemsetAsync(cnt, 0, (size_t)N * 4, stream);
        hipMemsetAsync(bump, 0, 64, stream);
        hipMemsetAsync(cursor_fb, 0, (size_t)N * 4, stream);
        k_count_slot<<<(E + 255) / 256, 256, 0, stream>>>(dst, cnt, col, E);
        k_dinv2<<<(N + 255) / 256, 256, 0, stream>>>(cnt, dinv, N);
        k_alloc<<<(N + 255) / 256, 256, 0, stream>>>(cnt, row_ptr, bump, N);
        k_fill<<<(E + 255) / 256, 256, 0, stream>>>(src, dst, row_ptr, cursor_fb, dinv, col, wgt_fb, E);
        const int gather_grid32 = (N * 32 + 255) / 256;
        k_gather<<<gather_grid32, 256, 0, stream>>>((const float4*)x_guide, dinv, row_ptr, cnt,
                                                    col, wgt_fb, (float4*)agg, N);
        k_gemm_couple<<<gemm_grid, 256, 0, stream>>>(agg, Ws1, bs1, Wt1, bt1, x_main, out_main, N);
        k_gather<<<gather_grid32, 256, 0, stream>>>((const float4*)out_main, dinv, row_ptr, cnt,
                                                    col, wgt_fb, (float4*)agg, N);
        k_gemm_couple<<<gemm_grid, 256, 0, stream>>>(agg, Ws2, bs2, Wt2, bt2, x_guide, out_guide, N);
    }
}

// Round 18
// 269.223 us; speedup vs baseline: 1.0545x; 1.0436x over previous
//
#include <hip/hip_runtime.h>
#include <cstdint>
#include <cstddef>

constexpr int DIMS = 128;

typedef __attribute__((ext_vector_type(8))) short bf16x8;
typedef __attribute__((ext_vector_type(8))) unsigned short ushort8v;
typedef __attribute__((ext_vector_type(4))) float f32x4;
typedef __attribute__((ext_vector_type(2))) float f32x2;

#if defined(__has_builtin)
# if __has_builtin(__builtin_amdgcn_cvt_pk_f32_fp8) && __has_builtin(__builtin_amdgcn_cvt_pk_fp8_f32)
#  define FP8_HW 1
# endif
#endif
#ifndef FP8_HW
# define FP8_HW 0
#endif

__device__ __forceinline__ unsigned short f2b(float f) {
    uint32_t u = __builtin_bit_cast(uint32_t, f);
    uint32_t r = (u + 0x7FFFu + ((u >> 16) & 1u)) >> 16;
    return (unsigned short)r;
}
__device__ __forceinline__ float b2f(unsigned short h) {
    uint32_t u = ((uint32_t)h) << 16;
    return __builtin_bit_cast(float, u);
}

// ---- fp8 e4m3fn helpers (HW cvt when available; manual fallback otherwise) ----
__device__ __forceinline__ float q2f_sw(unsigned char v) {
    uint32_t em = v & 0x7fu;
    float mag;
    if (em >= 0x08u) {
        uint32_t bits = (((em >> 3) + 120u) << 23) | ((em & 7u) << 20);
        mag = __builtin_bit_cast(float, bits);
    } else {
        mag = (float)em * 0.001953125f;
    }
    return (v & 0x80u) ? -mag : mag;
}
__device__ __forceinline__ unsigned char f2q_sw(float f) {
    uint32_t u = __builtin_bit_cast(uint32_t, f);
    uint32_t s = (u >> 24) & 0x80u;
    int e = (int)((u >> 23) & 0xffu) - 127;
    uint32_t m = u & 0x7fffffu;
    if (e < -9) return (unsigned char)s;
    if (e > 8) return (unsigned char)(s | 0x7eu);
    if (e >= -6) {
        uint32_t mant = m >> 20;
        uint32_t rem = m & 0xfffffu;
        uint32_t r = mant + ((rem > 0x80000u) || (rem == 0x80000u && (mant & 1u)));
        uint32_t v = (((uint32_t)(e + 7)) << 3) + r;
        if (v >= 0x7fu) v = 0x7eu;
        return (unsigned char)(s | v);
    }
    float scaled = fabsf(f) * 512.0f;
    int q = (int)(scaled + 0.5f);
    if (q > 8) q = 8;
    return (unsigned char)(s | (uint32_t)q);
}

__device__ __forceinline__ void fp8x8_fma(uint2 v, float w, float* acc) {
#if FP8_HW
    f32x2 a0 = __builtin_amdgcn_cvt_pk_f32_fp8((int)v.x, false);
    f32x2 a1 = __builtin_amdgcn_cvt_pk_f32_fp8((int)v.x, true);
    f32x2 a2 = __builtin_amdgcn_cvt_pk_f32_fp8((int)v.y, false);
    f32x2 a3 = __builtin_amdgcn_cvt_pk_f32_fp8((int)v.y, true);
    acc[0] = fmaf(w, a0[0], acc[0]); acc[1] = fmaf(w, a0[1], acc[1]);
    acc[2] = fmaf(w, a1[0], acc[2]); acc[3] = fmaf(w, a1[1], acc[3]);
    acc[4] = fmaf(w, a2[0], acc[4]); acc[5] = fmaf(w, a2[1], acc[5]);
    acc[6] = fmaf(w, a3[0], acc[6]); acc[7] = fmaf(w, a3[1], acc[7]);
#else
#pragma unroll
    for (int q = 0; q < 8; ++q) {
        unsigned char b = (unsigned char)(((q < 4 ? v.x : v.y) >> ((q & 3) * 8)) & 0xffu);
        acc[q] = fmaf(w, q2f_sw(b), acc[q]);
    }
#endif
}

__device__ __forceinline__ unsigned int fp8x4_pack(float a, float b, float c, float d) {
#if FP8_HW
    int r = 0;
    r = __builtin_amdgcn_cvt_pk_fp8_f32(a, b, r, false);
    r = __builtin_amdgcn_cvt_pk_fp8_f32(c, d, r, true);
    return (unsigned int)r;
#else
    return (unsigned int)f2q_sw(a) | ((unsigned int)f2q_sw(b) << 8) |
           ((unsigned int)f2q_sw(c) << 16) | ((unsigned int)f2q_sw(d) << 24);
#endif
}

// ================= bucketed CSR build (LDS atomics, packed edges) =================
__global__ __launch_bounds__(1024) void k_bhist(const int* __restrict__ dst,
                                                int* __restrict__ bktCnt,
                                                int E, int nbkt, int Ec) {
    __shared__ int lh[512];
    if (threadIdx.x < 512) lh[threadIdx.x] = 0;
    __syncthreads();
    int base = blockIdx.x * Ec;
    int end = min(E, base + Ec);
    for (int i = base + threadIdx.x; i < end; i += 1024)
        atomicAdd(&lh[dst[i] >> 9], 1);
    __syncthreads();
    if (threadIdx.x < nbkt) {
        int v = lh[threadIdx.x];
        if (v) atomicAdd(&bktCnt[threadIdx.x * 16], v);
    }
}

__global__ void k_bscan(const int* __restrict__ bktCnt, int* __restrict__ bktBase,
                        int* __restrict__ bktCursor, int nbkt, int E) {
    int lane = threadIdx.x;  // blockDim.x == 64
    int v[8]; int s = 0;
#pragma unroll
    for (int k = 0; k < 8; ++k) {
        int idx = lane * 8 + k;
        int c = (idx < nbkt) ? bktCnt[idx * 16] : 0;
        v[k] = s; s += c;
    }
    int x = s;
#pragma unroll
    for (int d = 1; d < 64; d <<= 1) {
        int y = __shfl_up(x, d);
        if (lane >= d) x += y;
    }
    int excl = x - s;
#pragma unroll
    for (int k = 0; k < 8; ++k) {
        int idx = lane * 8 + k;
        if (idx < nbkt) { int bb = excl + v[k]; bktBase[idx] = bb; bktCursor[idx * 16] = bb; }
    }
    if (lane == 0) bktBase[nbkt] = E;
}

__global__ __launch_bounds__(1024) void k_bscatter(const int* __restrict__ src,
                                                   const int* __restrict__ dst,
                                                   int* __restrict__ bktCursor,
                                                   unsigned int* __restrict__ epk,
                                                   int E, int nbkt, int Ec) {
    __shared__ int lh[512];
    __shared__ int lbase[512];
    __shared__ int lcur[512];
    if (threadIdx.x < 512) { lh[threadIdx.x] = 0; lcur[threadIdx.x] = 0; }
    __syncthreads();
    int base = blockIdx.x * Ec;
    int end = min(E, base + Ec);
    for (int i = base + threadIdx.x; i < end; i += 1024)
        atomicAdd(&lh[dst[i] >> 9], 1);
    __syncthreads();
    if (threadIdx.x < nbkt) {
        int c = lh[threadIdx.x];
        lbase[threadIdx.x] = c ? atomicAdd(&bktCursor[threadIdx.x * 16], c) : 0;
    }
    __syncthreads();
    for (int i = base + threadIdx.x; i < end; i += 1024) {
        int d = dst[i], s = src[i];
        int b = d >> 9;
        int r = atomicAdd(&lcur[b], 1);
        epk[lbase[b] + r] = ((unsigned int)s << 9) | (unsigned int)(d & 511);
    }
}

// per-bucket fine CSR in LDS; also emits dinv (fused)
__global__ __launch_bounds__(512) void k_bcsr(const unsigned int* __restrict__ epk,
                                              const int* __restrict__ bktBase,
                                              int* __restrict__ col, int* __restrict__ row_ptr,
                                              int* __restrict__ cnt, float* __restrict__ dinv,
                                              int N) {
    __shared__ int lcnt[512];
    __shared__ int loff[512];
    __shared__ int lcur[512];
    const int b = blockIdx.x;
    const int node0 = b << 9;
    lcnt[threadIdx.x] = 0; lcur[threadIdx.x] = 0;
    __syncthreads();
    const int ebeg = bktBase[b], eend = bktBase[b + 1];
    for (int i = ebeg + threadIdx.x; i < eend; i += 512)
        atomicAdd(&lcnt[epk[i] & 511u], 1);
    __syncthreads();
    if (threadIdx.x < 64) {
        int lane = threadIdx.x;
        int v[8]; int s = 0;
#pragma unroll
        for (int k = 0; k < 8; ++k) { v[k] = s; s += lcnt[lane * 8 + k]; }
        int x = s;
#pragma unroll
        for (int d = 1; d < 64; d <<= 1) { int y = __shfl_up(x, d); if (lane >= d) x += y; }
        int excl = x - s;
#pragma unroll
        for (int k = 0; k < 8; ++k) loff[lane * 8 + k] = excl + v[k];
    }
    __syncthreads();
    const int node = node0 + threadIdx.x;
    if (node < N) {
        int c = lcnt[threadIdx.x];
        row_ptr[node] = ebeg + loff[threadIdx.x];
        cnt[node] = c;
        dinv[node] = rsqrtf((float)(c + 1));
    }
    for (int i = ebeg + threadIdx.x; i < eend; i += 512) {
        unsigned int e = epk[i];
        int dl = e & 511u;
        int r = atomicAdd(&lcur[dl], 1);
        col[ebeg + loff[dl] + r] = (int)(e >> 9);
    }
}

// ================= old-path CSR kernels (fallback when nbkt > 512) =================
__global__ void k_count_slot(const int* __restrict__ dst, int* __restrict__ cnt,
                             int* __restrict__ slot, int E) {
    int e = blockIdx.x * blockDim.x + threadIdx.x;
    if (e < E) slot[e] = atomicAdd(&cnt[dst[e]], 1);
}

__global__ void k_alloc(const int* __restrict__ cnt, int* __restrict__ row_ptr,
                        int* __restrict__ bump, int N) {
    int i = blockIdx.x * blockDim.x + threadIdx.x;
    int lane = threadIdx.x & 63;
    int v = (i < N) ? cnt[i] : 0;
    int x = v;
#pragma unroll
    for (int d = 1; d < 64; d <<= 1) {
        int y = __shfl_up(x, d);
        if (lane >= d) x += y;
    }
    int total = __shfl(x, 63);
    int base = 0;
    if (lane == 0) base = atomicAdd(bump, total);
    base = __shfl(base, 0);
    if (i < N) row_ptr[i] = base + x - v;
}

__global__ void k_fill3(const int* __restrict__ src, const int* __restrict__ dst,
                        const int* __restrict__ row_ptr, const int* __restrict__ slot,
                        int* __restrict__ col, int E) {
    int e = blockIdx.x * blockDim.x + threadIdx.x;
    if (e >= E) return;
    col[row_ptr[dst[e]] + slot[e]] = src[e];
}

__global__ void k_dinv2(const int* __restrict__ cnt, float* __restrict__ dinv, int N) {
    int i = blockIdx.x * blockDim.x + threadIdx.x;
    if (i < N) dinv[i] = rsqrtf((float)(cnt[i] + 1));
}

// ---------------- f32 -> fp8 cast (8 elems/thread) ----------------
__global__ void k_cast_q(const float* __restrict__ X, unsigned char* __restrict__ Yq, int n8) {
    int i = blockIdx.x * blockDim.x + threadIdx.x;
    if (i >= n8) return;
    const float4* p = (const float4*)X + (size_t)i * 2;
    float4 a = p[0], b = p[1];
    uint2 q;
    q.x = fp8x4_pack(a.x, a.y, a.z, a.w);
    q.y = fp8x4_pack(b.x, b.y, b.z, b.w);
    *(uint2*)&Yq[(size_t)i * 8] = q;
}

__global__ void k_wpack4(const float* __restrict__ W0, const float* __restrict__ W1,
                         const float* __restrict__ W2, const float* __restrict__ W3,
                         unsigned short* __restrict__ out) {
    int t = blockIdx.x * blockDim.x + threadIdx.x;  // 0..2047
    if (t >= 2048) return;
    const float* W = (blockIdx.y == 0) ? W0 : (blockIdx.y == 1) ? W1
                   : (blockIdx.y == 2) ? W2 : W3;
    unsigned short* o = out + (size_t)blockIdx.y * 16384;
    int lane = t & 63;
    int nt = (t >> 6) & 7;
    int kk = t >> 9;
    int n = nt * 16 + (lane & 15);
    int k0 = kk * 32 + (lane >> 4) * 8;
    ushort8v h8;
#pragma unroll
    for (int j = 0; j < 8; ++j) h8[j] = f2b(W[(size_t)(k0 + j) * DIMS + n]);
    *(ushort8v*)&o[(size_t)t * 8] = h8;
}

// ---------------- gather: fp8 neighbors + f32 self, f32 accum, bf16 out ----------------
__global__ __launch_bounds__(256) void k_gather_q2(
    const unsigned char* __restrict__ Xq, const float* __restrict__ Xf,
    const float* __restrict__ dinv,
    const int* __restrict__ row_ptr, const int* __restrict__ cnt,
    const int* __restrict__ col, unsigned short* __restrict__ aggb, int N)
{
    int t = blockIdx.x * blockDim.x + threadIdx.x;
    int node = t >> 4;
    if (node >= N) return;
    const size_t base = (size_t)(t & 15) * 8;

    float ds = dinv[node];
    float w0 = ds * ds;
    const float4* sp = (const float4*)&Xf[(size_t)node * DIMS + base];
    float4 s0v = sp[0], s1v = sp[1];
    float acc[8];
    acc[0] = s0v.x * w0; acc[1] = s0v.y * w0; acc[2] = s0v.z * w0; acc[3] = s0v.w * w0;
    acc[4] = s1v.x * w0; acc[5] = s1v.y * w0; acc[6] = s1v.z * w0; acc[7] = s1v.w * w0;

    const int beg = row_ptr[node];
    const int m = cnt[node];
    int j = 0;
    for (; j + 1 < m; j += 2) {
        int n0 = col[beg + j], n1 = col[beg + j + 1];
        float wa = ds * dinv[n0], wb = ds * dinv[n1];
        uint2 v0 = *(const uint2*)&Xq[(size_t)n0 * DIMS + base];
        uint2 v1 = *(const uint2*)&Xq[(size_t)n1 * DIMS + base];
        fp8x8_fma(v0, wa, acc);
        fp8x8_fma(v1, wb, acc);
    }
    if (j < m) {
        int n0 = col[beg + j];
        float wa = ds * dinv[n0];
        uint2 v0 = *(const uint2*)&Xq[(size_t)n0 * DIMS + base];
        fp8x8_fma(v0, wa, acc);
    }
    ushort8v o;
#pragma unroll
    for (int q = 0; q < 8; ++q) o[q] = f2b(acc[q]);
    *(ushort8v*)&aggb[(size_t)node * DIMS + base] = o;
}

// ---------------- MFMA dual-GEMM + coupling, v5: column-half blocks, 32KB LDS ----------------
__global__ __launch_bounds__(256) void k_mfma_couple5(
    const unsigned short* __restrict__ Ab, const unsigned short* __restrict__ Wpk,
    const float* __restrict__ bs, const float* __restrict__ bt,
    const float* __restrict__ Xo, float* __restrict__ Out,
    unsigned char* Out8, int N, int nidx)
{
    __shared__ unsigned short lds[16384];  // 32 KB: Ws half | Wt half

    const int wave = threadIdx.x >> 6, lane = threadIdx.x & 63;
    const int rsub = lane & 15;
    const int ksub = (lane >> 4) * 8;
    const int csub = (lane >> 4) * 4;

    const int h = blockIdx.x & 1;

    for (int i = threadIdx.x; i < 2048; i += 256) {
        int wsel = i >> 10;
        int rem = i & 1023;
        int kk = rem >> 8;
        int ntl = (rem >> 6) & 3;
        int ln = rem & 63;
        int gfrag = (kk * 8 + h * 4 + ntl) * 64 + ln;
        *(ushort8v*)&lds[(size_t)i * 8] =
            *(const ushort8v*)&Wpk[((size_t)wsel * 16384) + (size_t)gfrag * 8];
    }
    __syncthreads();
    const unsigned short* wsf = lds;
    const unsigned short* wtf = lds + 8192;

    for (int idx = blockIdx.x; idx < nidx; idx += gridDim.x) {
        const int tile = idx >> 1;
        const int m = tile * 64 + wave * 16 + rsub;
        const int mld = (m < N) ? m : (N - 1);
        const bool valid = (m < N);

        bf16x8 af[4];
#pragma unroll
        for (int kk = 0; kk < 4; ++kk)
            af[kk] = *(const bf16x8*)&Ab[(size_t)mld * DIMS + kk * 32 + ksub];

        f32x4 acc_s[4], acc_t[4];
#pragma unroll
        for (int nt = 0; nt < 4; ++nt) {
            acc_s[nt] = (f32x4){0.f, 0.f, 0.f, 0.f};
            acc_t[nt] = (f32x4){0.f, 0.f, 0.f, 0.f};
        }

#pragma unroll
        for (int kk = 0; kk < 4; ++kk) {
#pragma unroll
            for (int nt = 0; nt < 4; ++nt) {
                const int fi = ((kk * 4 + nt) * 64 + lane) * 8;
                bf16x8 ws = *(const bf16x8*)&wsf[fi];
                bf16x8 wt = *(const bf16x8*)&wtf[fi];
                acc_s[nt] = __builtin_amdgcn_mfma_f32_16x16x32_bf16(ws, af[kk], acc_s[nt], 0, 0, 0);
                acc_t[nt] = __builtin_amdgcn_mfma_f32_16x16x32_bf16(wt, af[kk], acc_t[nt], 0, 0, 0);
            }
        }

        if (valid) {
#pragma unroll
            for (int nt = 0; nt < 4; ++nt) {
                const int c4 = (h * 4 + nt) * 16 + csub;
                float4 bsv = *(const float4*)&bs[c4];
                float4 btv = *(const float4*)&bt[c4];
                float4 xo  = *(const float4*)&Xo[(size_t)m * DIMS + c4];
                float4 o;
                o.x = xo.x * expf(tanhf(acc_s[nt][0] + bsv.x)) + (acc_t[nt][0] + btv.x);
                o.y = xo.y * expf(tanhf(acc_s[nt][1] + bsv.y)) + (acc_t[nt][1] + btv.y);
                o.z = xo.z * expf(tanhf(acc_s[nt][2] + bsv.z)) + (acc_t[nt][2] + btv.z);
                o.w = xo.w * expf(tanhf(acc_s[nt][3] + bsv.w)) + (acc_t[nt][3] + btv.w);
                *(float4*)&Out[(size_t)m * DIMS + c4] = o;
                if (Out8) {
                    *(unsigned int*)&Out8[(size_t)m * DIMS + c4] =
                        fp8x4_pack(o.x, o.y, o.z, o.w);
                }
            }
        }
    }
}

// ---------------- f32 fallback kernels ----------------
__global__ void k_fill(const int* __restrict__ src, const int* __restrict__ dst,
                       const int* __restrict__ row_ptr, int* __restrict__ cursor,
                       const float* __restrict__ dinv,
                       int* __restrict__ col, float* __restrict__ wgt, int E) {
    int e = blockIdx.x * blockDim.x + threadIdx.x;
    if (e >= E) return;
    int s = src[e], d = dst[e];
    int pos = row_ptr[d] + atomicAdd(&cursor[d], 1);
    col[pos] = s;
    wgt[pos] = dinv[s] * dinv[d];
}

__global__ __launch_bounds__(256) void k_gather(
    const float4* __restrict__ X4, const float* __restrict__ dinv,
    const int* __restrict__ row_ptr, const int* __restrict__ cnt,
    const int* __restrict__ col, const float* __restrict__ wgt,
    float4* __restrict__ agg4, int N)
{
    int t = blockIdx.x * blockDim.x + threadIdx.x;
    int node = t >> 5;
    if (node >= N) return;
    int lane = t & 31;
    float ds = dinv[node];
    float w0 = ds * ds;
    float4 acc = X4[(size_t)node * 32 + lane];
    acc.x *= w0; acc.y *= w0; acc.z *= w0; acc.w *= w0;
    int beg = row_ptr[node];
    int m = cnt[node];
    for (int j = 0; j < m; ++j) {
        int s0 = col[beg + j];
        float wa = wgt[beg + j];
        float4 v0 = X4[(size_t)s0 * 32 + lane];
        acc.x = fmaf(wa, v0.x, acc.x); acc.y = fmaf(wa, v0.y, acc.y);
        acc.z = fmaf(wa, v0.z, acc.z); acc.w = fmaf(wa, v0.w, acc.w);
    }
    agg4[(size_t)node * 32 + lane] = acc;
}

__global__ __launch_bounds__(256) void k_gemm_couple(
    const float* A, const float* __restrict__ Ws, const float* __restrict__ bs,
    const float* __restrict__ Wt, const float* __restrict__ bt,
    const float* __restrict__ Xo, float* Out, int N)
{
    constexpr int TM = 64, TK = 16;
    __shared__ float As[TK][TM + 4];
    __shared__ float Ss[TK][DIMS];
    __shared__ float St[TK][DIMS];
    const int tid = threadIdx.x;
    const int ty = tid >> 4, tx = tid & 15;
    const int r0 = ty * 4, c0 = tx * 8;
    const int block_row = blockIdx.x * TM;

    float acc_s[4][8], acc_t[4][8];
#pragma unroll
    for (int r = 0; r < 4; ++r)
#pragma unroll
        for (int c = 0; c < 8; ++c) { acc_s[r][c] = 0.f; acc_t[r][c] = 0.f; }

    const int ar = tid >> 2;
    const int aq = tid & 3;
    int arow = block_row + ar;
    if (arow >= N) arow = N - 1;

    for (int k0 = 0; k0 < DIMS; k0 += TK) {
        __syncthreads();
        {
            float4 v = *(const float4*)&A[(size_t)arow * DIMS + k0 + aq * 4];
            As[aq * 4 + 0][ar] = v.x;
            As[aq * 4 + 1][ar] = v.y;
            As[aq * 4 + 2][ar] = v.z;
            As[aq * 4 + 3][ar] = v.w;
        }
#pragma unroll
        for (int i = 0; i < 2; ++i) {
            int idx = tid + i * 256;
            int kk = idx >> 5;
            int j4 = idx & 31;
            *(float4*)&Ss[kk][j4 * 4] = *(const float4*)&Ws[(size_t)(k0 + kk) * DIMS + j4 * 4];
            *(float4*)&St[kk][j4 * 4] = *(const float4*)&Wt[(size_t)(k0 + kk) * DIMS + j4 * 4];
        }
        __syncthreads();
#pragma unroll
        for (int k = 0; k < TK; ++k) {
            float4 av = *(const float4*)&As[k][r0];
            float a[4] = {av.x, av.y, av.z, av.w};
            float ws8[8], wt8[8];
            *(float4*)&ws8[0] = *(const float4*)&Ss[k][c0];
            *(float4*)&ws8[4] = *(const float4*)&Ss[k][c0 + 4];
            *(float4*)&wt8[0] = *(const float4*)&St[k][c0];
            *(float4*)&wt8[4] = *(const float4*)&St[k][c0 + 4];
#pragma unroll
            for (int r = 0; r < 4; ++r)
#pragma unroll
                for (int c = 0; c < 8; ++c) {
                    acc_s[r][c] = fmaf(a[r], ws8[c], acc_s[r][c]);
                    acc_t[r][c] = fmaf(a[r], wt8[c], acc_t[r][c]);
                }
        }
    }

    float bsv[8], btv[8];
    *(float4*)&bsv[0] = *(const float4*)&bs[c0];
    *(float4*)&bsv[4] = *(const float4*)&bs[c0 + 4];
    *(float4*)&btv[0] = *(const float4*)&bt[c0];
    *(float4*)&btv[4] = *(const float4*)&bt[c0 + 4];
#pragma unroll
    for (int r = 0; r < 4; ++r) {
        int row = block_row + r0 + r;
        if (row < N) {
            float xo[8];
            *(float4*)&xo[0] = *(const float4*)&Xo[(size_t)row * DIMS + c0];
            *(float4*)&xo[4] = *(const float4*)&Xo[(size_t)row * DIMS + c0 + 4];
            float o[8];
#pragma unroll
            for (int c = 0; c < 8; ++c) {
                float s = tanhf(acc_s[r][c] + bsv[c]);
                float t = acc_t[r][c] + btv[c];
                o[c] = xo[c] * expf(s) + t;
            }
            *(float4*)&Out[(size_t)row * DIMS + c0] = *(const float4*)&o[0];
            *(float4*)&Out[(size_t)row * DIMS + c0 + 4] = *(const float4*)&o[4];
        }
    }
}

extern "C" void kernel_launch(void* const* d_in, const int* in_sizes, int n_in,
                              void* d_out, int out_size, void* d_ws, size_t ws_size,
                              hipStream_t stream) {
    const float* x_main  = (const float*)d_in[0];
    const float* x_guide = (const float*)d_in[1];
    const int*   ei      = (const int*)d_in[2];
    const float* Ws1 = (const float*)d_in[3];
    const float* bs1 = (const float*)d_in[4];
    const float* Wt1 = (const float*)d_in[5];
    const float* bt1 = (const float*)d_in[6];
    const float* Ws2 = (const float*)d_in[7];
    const float* bs2 = (const float*)d_in[8];
    const float* Wt2 = (const float*)d_in[9];
    const float* bt2 = (const float*)d_in[10];

    const int N = in_sizes[0] / DIMS;
    const int E = in_sizes[2] / 2;
    const int* src = ei;
    const int* dst = ei + E;

    float* out_main  = (float*)d_out;
    float* out_guide = out_main + (size_t)N * DIMS;

    // ---- ws layout ----
    char* w = (char*)d_ws;
    size_t off = 0;
    auto alloc = [&](size_t bytes) { size_t o = off; off = (off + bytes + 15) & ~(size_t)15; return o; };
    int*   cnt      = (int*)(w + alloc((size_t)N * 4));
    int*   row_ptr  = (int*)(w + alloc((size_t)N * 4));
    int*   bump     = (int*)(w + alloc(64));
    int*   bktCnt    = (int*)(w + alloc(512 * 16 * 4));
    int*   bktCursor = (int*)(w + alloc(512 * 16 * 4));
    int*   bktBase   = (int*)(w + alloc(513 * 4));
    float* dinv     = (float*)(w + alloc((size_t)N * 4));
    int*   col      = (int*)(w + alloc((size_t)E * 4));
    size_t base_end = off;
    unsigned char*  xq   = (unsigned char*)(w + alloc((size_t)N * DIMS));
    unsigned short* aggb = (unsigned short*)(w + alloc((size_t)N * DIMS * 2));
    unsigned short* wpk  = (unsigned short*)(w + alloc((size_t)4 * 16384 * 2));
    size_t needed_fp8 = off;
    int*          slot = (int*)aggb;
    unsigned int* epk  = (unsigned int*)aggb;
    int*   cursor_fb = (int*)(w + base_end);
    float* wgt_fb    = (float*)(w + base_end + (((size_t)N * 4 + 15) & ~(size_t)15));
    size_t needed_f32 = base_end + ((size_t)N * 4 + 16) + (size_t)E * 4;

    const int gemm_grid  = (N + 63) / 64;
    const int ntiles64   = (N + 63) / 64;
    const int nidx       = ntiles64 * 2;
    int mfma_grid        = (nidx < 1024) ? nidx : 1024;
    mfma_grid            = (mfma_grid + 1) & ~1;

    const int nbkt = (N + 511) >> 9;
    const bool bucketed_ok = (nbkt <= 512) && (N < (1 << 23)) &&
                             ((size_t)E * 4 <= (size_t)N * DIMS * 2);

    if (ws_size >= needed_fp8) {
        // ---- CSR build ----
        if (bucketed_ok) {
            const int Ec = (E + 255) / 256;
            hipMemsetAsync(bktCnt, 0, (size_t)nbkt * 16 * 4, stream);
            k_bhist<<<256, 1024, 0, stream>>>(dst, bktCnt, E, nbkt, Ec);
            k_bscan<<<1, 64, 0, stream>>>(bktCnt, bktBase, bktCursor, nbkt, E);
            k_bscatter<<<256, 1024, 0, stream>>>(src, dst, bktCursor, epk, E, nbkt, Ec);
            k_bcsr<<<nbkt, 512, 0, stream>>>(epk, bktBase, col, row_ptr, cnt, dinv, N);
        } else {
            hipMemsetAsync(cnt, 0, (size_t)N * 4, stream);
            hipMemsetAsync(bump, 0, 64, stream);
            k_count_slot<<<(E + 255) / 256, 256, 0, stream>>>(dst, cnt, slot, E);
            k_alloc<<<(N + 255) / 256, 256, 0, stream>>>(cnt, row_ptr, bump, N);
            k_fill3<<<(E + 255) / 256, 256, 0, stream>>>(src, dst, row_ptr, slot, col, E);
            k_dinv2<<<(N + 255) / 256, 256, 0, stream>>>(cnt, dinv, N);
        }

        k_wpack4<<<dim3(8, 4), 256, 0, stream>>>(Ws1, Wt1, Ws2, Wt2, wpk);
        unsigned short* W1pk = wpk;
        unsigned short* W2pk = wpk + 2 * 16384;

        const int n8 = N * DIMS / 8;
        k_cast_q<<<(n8 + 255) / 256, 256, 0, stream>>>(x_guide, xq, n8);

        const int gather_grid = (N * 16 + 255) / 256;
        // ---- stage 1: neighbors fp8(x_guide), self f32 x_guide ----
        k_gather_q2<<<gather_grid, 256, 0, stream>>>(xq, x_guide, dinv, row_ptr, cnt, col, aggb, N);
        k_mfma_couple5<<<mfma_grid, 256, 0, stream>>>(aggb, W1pk, bs1, bt1, x_main,
                                                      out_main, xq, N, nidx);
        // ---- stage 2: neighbors fp8(out_main), self f32 out_main ----
        k_gather_q2<<<gather_grid, 256, 0, stream>>>(xq, out_main, dinv, row_ptr, cnt, col, aggb, N);
        k_mfma_couple5<<<mfma_grid, 256, 0, stream>>>(aggb, W2pk, bs2, bt2, x_guide,
                                                      out_guide, nullptr, N, nidx);
    } else if (ws_size >= needed_f32) {
        float* agg = out_guide;
        hipMemsetAsync(cnt, 0, (size_t)N * 4, stream);
        hipMemsetAsync(bump, 0, 64, stream);
        hipMemsetAsync(cursor_fb, 0, (size_t)N * 4, stream);
        k_count_slot<<<(E + 255) / 256, 256, 0, stream>>>(dst, cnt, col, E);
        k_dinv2<<<(N + 255) / 256, 256, 0, stream>>>(cnt, dinv, N);
        k_alloc<<<(N + 255) / 256, 256, 0, stream>>>(cnt, row_ptr, bump, N);
        k_fill<<<(E + 255) / 256, 256, 0, stream>>>(src, dst, row_ptr, cursor_fb, dinv, col, wgt_fb, E);
        const int gather_grid32 = (N * 32 + 255) / 256;
        k_gather<<<gather_grid32, 256, 0, stream>>>((const float4*)x_guide, dinv, row_ptr, cnt,
                                                    col, wgt_fb, (float4*)agg, N);
        k_gemm_couple<<<gemm_grid, 256, 0, stream>>>(agg, Ws1, bs1, Wt1, bt1, x_main, out_main, N);
        k_gather<<<gather_grid32, 256, 0, stream>>>((const float4*)out_main, dinv, row_ptr, cnt,
                                                    col, wgt_fb, (float4*)agg, N);
        k_gemm_couple<<<gemm_grid, 256, 0, stream>>>(agg, Ws2, bs2, Wt2, bt2, x_guide, out_guide, N);
    }
}